// Round 2
// baseline (229.940 us; speedup 1.0000x reference)
//
#include <hip/hip_runtime.h>

// Shapes fixed by setup_inputs(): B=4, L=2048, D=2048. All I/O fp32.
#define BB 4
#define LL 2048
#define DD 2048
#define DTC 0.01f

// ---- K1: partial column-sum over L chunks; atomicAdd into xsum[b*D+d] ----
// grid (L/16, B), block 256; thread owns 8 consecutive d (two float4 per row).
__global__ __launch_bounds__(256) void k_mean_partial(
        const float* __restrict__ x, float* __restrict__ xsum) {
    const int CH = 16;
    int b  = blockIdx.y;
    int l0 = blockIdx.x * CH;
    int d0 = threadIdx.x << 3;
    const float* p = x + ((size_t)(b * LL + l0)) * DD + d0;
    float acc[8];
#pragma unroll
    for (int k = 0; k < 8; k++) acc[k] = 0.f;
    for (int l = 0; l < CH; l++) {
        float4 a = *(const float4*)(p + (size_t)l * DD);
        float4 c = *(const float4*)(p + (size_t)l * DD + 4);
        acc[0] += a.x; acc[1] += a.y; acc[2] += a.z; acc[3] += a.w;
        acc[4] += c.x; acc[5] += c.y; acc[6] += c.z; acc[7] += c.w;
    }
    float* dst = xsum + b * DD + d0;
#pragma unroll
    for (int k = 0; k < 8; k++) atomicAdd(dst + k, acc[k]);
}

// ---- K2a: gm[b,i] = (1/L) * sum_j h_proj[i,j] * xsum[b,j] ----
// one wave per i; block = 4 waves; grid D/4.
__global__ __launch_bounds__(256) void k_gm(
        const float* __restrict__ hproj,
        const float* __restrict__ xsum, float* __restrict__ gm) {
    int wave = threadIdx.x >> 6, lane = threadIdx.x & 63;
    int i = (blockIdx.x << 2) + wave;
    const float* row = hproj + (size_t)i * DD;
    float acc[BB] = {0.f, 0.f, 0.f, 0.f};
    for (int j0 = lane * 8; j0 < DD; j0 += 64 * 8) {
        float4 h0 = *(const float4*)(row + j0);
        float4 h1 = *(const float4*)(row + j0 + 4);
#pragma unroll
        for (int b = 0; b < BB; b++) {
            float4 xa = *(const float4*)(xsum + b * DD + j0);
            float4 xb = *(const float4*)(xsum + b * DD + j0 + 4);
            acc[b] += h0.x*xa.x + h0.y*xa.y + h0.z*xa.z + h0.w*xa.w
                    + h1.x*xb.x + h1.y*xb.y + h1.z*xb.z + h1.w*xb.w;
        }
    }
#pragma unroll
    for (int b = 0; b < BB; b++) {
#pragma unroll
        for (int off = 32; off > 0; off >>= 1) acc[b] += __shfl_down(acc[b], off);
    }
    if (lane == 0) {
#pragma unroll
        for (int b = 0; b < BB; b++) gm[b * DD + i] = acc[b] * (1.0f / LL);
    }
}

// ---- K2b-row: delta[b,i] += DT*( sum_j gm[b,j]*jup[i,j] - gm[b,i]*softplus(r_i) )
__global__ __launch_bounds__(256) void k_delta_row(
        const float* __restrict__ jup,
        const float* __restrict__ rdiag,
        const float* __restrict__ gm, float* __restrict__ delta) {
    int wave = threadIdx.x >> 6, lane = threadIdx.x & 63;
    int i = (blockIdx.x << 2) + wave;
    const float* row = jup + (size_t)i * DD;
    float acc[BB] = {0.f, 0.f, 0.f, 0.f};
    for (int j0 = lane * 8; j0 < DD; j0 += 64 * 8) {
        float4 h0 = *(const float4*)(row + j0);
        float4 h1 = *(const float4*)(row + j0 + 4);
#pragma unroll
        for (int b = 0; b < BB; b++) {
            float4 ga = *(const float4*)(gm + b * DD + j0);
            float4 gb = *(const float4*)(gm + b * DD + j0 + 4);
            acc[b] += h0.x*ga.x + h0.y*ga.y + h0.z*ga.z + h0.w*ga.w
                    + h1.x*gb.x + h1.y*gb.y + h1.z*gb.z + h1.w*gb.w;
        }
    }
#pragma unroll
    for (int b = 0; b < BB; b++) {
#pragma unroll
        for (int off = 32; off > 0; off >>= 1) acc[b] += __shfl_down(acc[b], off);
    }
    if (lane == 0) {
        float r = log1pf(expf(rdiag[i]));  // softplus
#pragma unroll
        for (int b = 0; b < BB; b++)
            atomicAdd(delta + b * DD + i, DTC * (acc[b] - gm[b * DD + i] * r));
    }
}

// ---- K2b-col: delta[b,i] -= DT * sum_j gm[b,j]*jup[j,i]  (column access) ----
// grid (D/256, D/256): thread owns column i, block owns a 256-wide j chunk.
__global__ __launch_bounds__(256) void k_delta_col(
        const float* __restrict__ jup,
        const float* __restrict__ gm, float* __restrict__ delta) {
    int i  = blockIdx.x * 256 + threadIdx.x;
    int j0 = blockIdx.y * 256;
    float acc[BB] = {0.f, 0.f, 0.f, 0.f};
    for (int j = j0; j < j0 + 256; j++) {
        float v = jup[(size_t)j * DD + i];
#pragma unroll
        for (int b = 0; b < BB; b++) acc[b] += gm[b * DD + j] * v;
    }
#pragma unroll
    for (int b = 0; b < BB; b++) atomicAdd(delta + b * DD + i, -DTC * acc[b]);
}

// ---- K3: main pass. One block per (b,l) row. x' = x + delta[b]; l2-normalize;
// Chebyshev(deg 8); out = x' + 0.1*cheb. float4 I/O. ----
__global__ __launch_bounds__(256) void k_main(
        const float* __restrict__ x,
        const float* __restrict__ delta,
        const float* __restrict__ coeffs,
        float* __restrict__ out) {
    int row = blockIdx.x;           // 0 .. B*L-1
    int b   = row >> 11;            // L = 2048
    int d0  = threadIdx.x << 3;
    size_t base = (size_t)row * DD + d0;

    float4 va = *(const float4*)(x + base);
    float4 vb = *(const float4*)(x + base + 4);
    float xv[8] = {va.x, va.y, va.z, va.w, vb.x, vb.y, vb.z, vb.w};
    const float* dl = delta + b * DD + d0;
    float4 da = *(const float4*)dl;
    float4 db = *(const float4*)(dl + 4);
    xv[0] += da.x; xv[1] += da.y; xv[2] += da.z; xv[3] += da.w;
    xv[4] += db.x; xv[5] += db.y; xv[6] += db.z; xv[7] += db.w;

    float ss = 0.f;
#pragma unroll
    for (int k = 0; k < 8; k++) ss += xv[k] * xv[k];
#pragma unroll
    for (int off = 32; off > 0; off >>= 1) ss += __shfl_down(ss, off);
    __shared__ float sred[4];
    int wid = threadIdx.x >> 6, lane = threadIdx.x & 63;
    if (lane == 0) sred[wid] = ss;
    __syncthreads();
    float total = sred[0] + sred[1] + sred[2] + sred[3];
    float rinv = rsqrtf(fmaxf(total, 1e-8f));

    float c[9];
#pragma unroll
    for (int k = 0; k < 9; k++) c[k] = coeffs[k];

    float o[8];
#pragma unroll
    for (int k = 0; k < 8; k++) {
        float xn = xv[k] * rinv;
        float tp = 1.0f, tc = xn;
        float r = c[0] + c[1] * xn;
#pragma unroll
        for (int n = 2; n <= 8; n++) {
            float tn = 2.0f * xn * tc - tp;
            r += c[n] * tn;
            tp = tc; tc = tn;
        }
        o[k] = xv[k] + 0.1f * r;
    }
    float4 oa = {o[0], o[1], o[2], o[3]};
    float4 ob = {o[4], o[5], o[6], o[7]};
    *(float4*)(out + base)     = oa;
    *(float4*)(out + base + 4) = ob;
}

extern "C" void kernel_launch(void* const* d_in, const int* in_sizes, int n_in,
                              void* d_out, int out_size, void* d_ws, size_t ws_size,
                              hipStream_t stream) {
    (void)in_sizes; (void)n_in; (void)out_size; (void)ws_size;
    const float* x      = (const float*)d_in[0];
    const float* jup    = (const float*)d_in[1];
    const float* rdiag  = (const float*)d_in[2];
    const float* hproj  = (const float*)d_in[3];
    const float* coeffs = (const float*)d_in[4];
    float* out = (float*)d_out;

    float* ws    = (float*)d_ws;
    float* xsum  = ws;                 // B*D fp32 (atomic accum)
    float* delta = ws + BB * DD;       // B*D fp32 (atomic accum)
    float* gm    = ws + 2 * BB * DD;   // B*D fp32

    // zero the two atomic-accumulated regions (ws is poisoned 0xAA each call)
    hipMemsetAsync(d_ws, 0, (size_t)(2 * BB * DD) * sizeof(float), stream);

    k_mean_partial<<<dim3(LL / 16, BB), 256, 0, stream>>>(x, xsum);
    k_gm<<<DD / 4, 256, 0, stream>>>(hproj, xsum, gm);
    k_delta_row<<<DD / 4, 256, 0, stream>>>(jup, rdiag, gm, delta);
    k_delta_col<<<dim3(DD / 256, DD / 256), 256, 0, stream>>>(jup, gm, delta);
    k_main<<<BB * LL, 256, 0, stream>>>(x, delta, coeffs, out);
}

// Round 3
// 219.532 us; speedup vs baseline: 1.0474x; 1.0474x over previous
//
#include <hip/hip_runtime.h>

// Shapes fixed by setup_inputs(): B=4, L=2048, D=2048. All I/O fp32.
#define BB 4
#define LL 2048
#define DD 2048
#define DTC 0.01f

// ---- K1: partial column-sum over L chunks; atomicAdd into xsum[b*D+d] ----
// grid (L/16, B), block 256; thread owns 8 consecutive d.
// All 32 float4 loads issued before any accumulation (latency -> bandwidth).
__global__ __launch_bounds__(256) void k_mean_partial(
        const float* __restrict__ x, float* __restrict__ xsum) {
    const int CH = 16;
    int b  = blockIdx.y;
    int l0 = blockIdx.x * CH;
    int d0 = threadIdx.x << 3;
    const float* p = x + ((size_t)(b * LL + l0)) * DD + d0;

    float4 v[2 * CH];
#pragma unroll
    for (int l = 0; l < CH; l++) {
        v[2 * l]     = *(const float4*)(p + (size_t)l * DD);
        v[2 * l + 1] = *(const float4*)(p + (size_t)l * DD + 4);
    }
    float acc[8] = {0.f, 0.f, 0.f, 0.f, 0.f, 0.f, 0.f, 0.f};
#pragma unroll
    for (int l = 0; l < CH; l++) {
        acc[0] += v[2*l].x;   acc[1] += v[2*l].y;
        acc[2] += v[2*l].z;   acc[3] += v[2*l].w;
        acc[4] += v[2*l+1].x; acc[5] += v[2*l+1].y;
        acc[6] += v[2*l+1].z; acc[7] += v[2*l+1].w;
    }
    float* dst = xsum + b * DD + d0;
#pragma unroll
    for (int k = 0; k < 8; k++) atomicAdd(dst + k, acc[k]);
}

// ---- K2a: gm[b,i] = (1/L) * sum_j h_proj[i,j] * xsum[b,j] ----
// one wave per row i; block = 4 waves; grid D/4. Full row slice preloaded.
__global__ __launch_bounds__(256) void k_gm(
        const float* __restrict__ hproj,
        const float* __restrict__ xsum, float* __restrict__ gm) {
    int wave = threadIdx.x >> 6, lane = threadIdx.x & 63;
    int i = (blockIdx.x << 2) + wave;
    const float* row = hproj + (size_t)i * DD + lane * 8;

    float4 h[8];
#pragma unroll
    for (int t = 0; t < 4; t++) {
        h[2 * t]     = *(const float4*)(row + t * 512);
        h[2 * t + 1] = *(const float4*)(row + t * 512 + 4);
    }
    float acc[BB] = {0.f, 0.f, 0.f, 0.f};
#pragma unroll
    for (int t = 0; t < 4; t++) {
        int j0 = lane * 8 + t * 512;
#pragma unroll
        for (int b = 0; b < BB; b++) {
            float4 xa = *(const float4*)(xsum + b * DD + j0);
            float4 xb = *(const float4*)(xsum + b * DD + j0 + 4);
            acc[b] += h[2*t].x*xa.x + h[2*t].y*xa.y + h[2*t].z*xa.z + h[2*t].w*xa.w
                    + h[2*t+1].x*xb.x + h[2*t+1].y*xb.y + h[2*t+1].z*xb.z + h[2*t+1].w*xb.w;
        }
    }
#pragma unroll
    for (int b = 0; b < BB; b++) {
#pragma unroll
        for (int off = 32; off > 0; off >>= 1) acc[b] += __shfl_down(acc[b], off);
    }
    if (lane == 0) {
#pragma unroll
        for (int b = 0; b < BB; b++) gm[b * DD + i] = acc[b] * (1.0f / LL);
    }
}

// ---- K2b-row: delta[b,i] += DT*( sum_j gm[b,j]*jup[i,j] - gm[b,i]*softplus(r_i) )
__global__ __launch_bounds__(256) void k_delta_row(
        const float* __restrict__ jup,
        const float* __restrict__ rdiag,
        const float* __restrict__ gm, float* __restrict__ delta) {
    int wave = threadIdx.x >> 6, lane = threadIdx.x & 63;
    int i = (blockIdx.x << 2) + wave;
    const float* row = jup + (size_t)i * DD + lane * 8;

    float4 h[8];
#pragma unroll
    for (int t = 0; t < 4; t++) {
        h[2 * t]     = *(const float4*)(row + t * 512);
        h[2 * t + 1] = *(const float4*)(row + t * 512 + 4);
    }
    float acc[BB] = {0.f, 0.f, 0.f, 0.f};
#pragma unroll
    for (int t = 0; t < 4; t++) {
        int j0 = lane * 8 + t * 512;
#pragma unroll
        for (int b = 0; b < BB; b++) {
            float4 ga = *(const float4*)(gm + b * DD + j0);
            float4 gb = *(const float4*)(gm + b * DD + j0 + 4);
            acc[b] += h[2*t].x*ga.x + h[2*t].y*ga.y + h[2*t].z*ga.z + h[2*t].w*ga.w
                    + h[2*t+1].x*gb.x + h[2*t+1].y*gb.y + h[2*t+1].z*gb.z + h[2*t+1].w*gb.w;
        }
    }
#pragma unroll
    for (int b = 0; b < BB; b++) {
#pragma unroll
        for (int off = 32; off > 0; off >>= 1) acc[b] += __shfl_down(acc[b], off);
    }
    if (lane == 0) {
        float r = log1pf(expf(rdiag[i]));  // softplus
#pragma unroll
        for (int b = 0; b < BB; b++)
            atomicAdd(delta + b * DD + i, DTC * (acc[b] - gm[b * DD + i] * r));
    }
}

// ---- K2b-col: delta[b,i] -= DT * sum_j gm[b,j]*jup[j,i]  (column access) ----
// grid (D/256, D/32) = (8,64) = 512 blocks; thread owns column i, block owns
// a 32-wide j chunk. All 32 coalesced loads preloaded.
__global__ __launch_bounds__(256) void k_delta_col(
        const float* __restrict__ jup,
        const float* __restrict__ gm, float* __restrict__ delta) {
    const int JT = 32;
    int i  = blockIdx.x * 256 + threadIdx.x;
    int j0 = blockIdx.y * JT;

    float jv[JT];
#pragma unroll
    for (int jj = 0; jj < JT; jj++)
        jv[jj] = jup[(size_t)(j0 + jj) * DD + i];

    float acc[BB] = {0.f, 0.f, 0.f, 0.f};
#pragma unroll
    for (int jj = 0; jj < JT; jj++) {
#pragma unroll
        for (int b = 0; b < BB; b++)
            acc[b] += gm[b * DD + j0 + jj] * jv[jj];
    }
#pragma unroll
    for (int b = 0; b < BB; b++) atomicAdd(delta + b * DD + i, -DTC * acc[b]);
}

// ---- K3: main pass. One block per (b,l) row. x' = x + delta[b]; l2-normalize;
// Chebyshev(deg 8); out = x' + 0.1*cheb. float4 I/O. ----
__global__ __launch_bounds__(256) void k_main(
        const float* __restrict__ x,
        const float* __restrict__ delta,
        const float* __restrict__ coeffs,
        float* __restrict__ out) {
    int row = blockIdx.x;           // 0 .. B*L-1
    int b   = row >> 11;            // L = 2048
    int d0  = threadIdx.x << 3;
    size_t base = (size_t)row * DD + d0;

    float4 va = *(const float4*)(x + base);
    float4 vb = *(const float4*)(x + base + 4);
    const float* dl = delta + b * DD + d0;
    float4 da = *(const float4*)dl;
    float4 db = *(const float4*)(dl + 4);
    float xv[8] = {va.x + da.x, va.y + da.y, va.z + da.z, va.w + da.w,
                   vb.x + db.x, vb.y + db.y, vb.z + db.z, vb.w + db.w};

    float ss = 0.f;
#pragma unroll
    for (int k = 0; k < 8; k++) ss += xv[k] * xv[k];
#pragma unroll
    for (int off = 32; off > 0; off >>= 1) ss += __shfl_down(ss, off);
    __shared__ float sred[4];
    int wid = threadIdx.x >> 6, lane = threadIdx.x & 63;
    if (lane == 0) sred[wid] = ss;
    __syncthreads();
    float total = sred[0] + sred[1] + sred[2] + sred[3];
    float rinv = rsqrtf(fmaxf(total, 1e-8f));

    float c[9];
#pragma unroll
    for (int k = 0; k < 9; k++) c[k] = coeffs[k];

    float o[8];
#pragma unroll
    for (int k = 0; k < 8; k++) {
        float xn = xv[k] * rinv;
        float tp = 1.0f, tc = xn;
        float r = c[0] + c[1] * xn;
#pragma unroll
        for (int n = 2; n <= 8; n++) {
            float tn = 2.0f * xn * tc - tp;
            r += c[n] * tn;
            tp = tc; tc = tn;
        }
        o[k] = xv[k] + 0.1f * r;
    }
    float4 oa = {o[0], o[1], o[2], o[3]};
    float4 ob = {o[4], o[5], o[6], o[7]};
    *(float4*)(out + base)     = oa;
    *(float4*)(out + base + 4) = ob;
}

extern "C" void kernel_launch(void* const* d_in, const int* in_sizes, int n_in,
                              void* d_out, int out_size, void* d_ws, size_t ws_size,
                              hipStream_t stream) {
    (void)in_sizes; (void)n_in; (void)out_size; (void)ws_size;
    const float* x      = (const float*)d_in[0];
    const float* jup    = (const float*)d_in[1];
    const float* rdiag  = (const float*)d_in[2];
    const float* hproj  = (const float*)d_in[3];
    const float* coeffs = (const float*)d_in[4];
    float* out = (float*)d_out;

    float* ws    = (float*)d_ws;
    float* xsum  = ws;                 // B*D fp32 (atomic accum)
    float* delta = ws + BB * DD;       // B*D fp32 (atomic accum)
    float* gm    = ws + 2 * BB * DD;   // B*D fp32

    // zero the two atomic-accumulated regions (ws is poisoned 0xAA each call)
    hipMemsetAsync(d_ws, 0, (size_t)(2 * BB * DD) * sizeof(float), stream);

    k_mean_partial<<<dim3(LL / 16, BB), 256, 0, stream>>>(x, xsum);
    k_gm<<<DD / 4, 256, 0, stream>>>(hproj, xsum, gm);
    k_delta_row<<<DD / 4, 256, 0, stream>>>(jup, rdiag, gm, delta);
    k_delta_col<<<dim3(DD / 256, DD / 32), 256, 0, stream>>>(jup, gm, delta);
    k_main<<<BB * LL, 256, 0, stream>>>(x, delta, coeffs, out);
}

// Round 4
// 195.802 us; speedup vs baseline: 1.1743x; 1.1212x over previous
//
#include <hip/hip_runtime.h>

// Shapes fixed by setup_inputs(): B=4, L=2048, D=2048. All I/O fp32.
#define BB 4
#define LL 2048
#define DD 2048
#define DTC 0.01f

// ---- K1: partial column-sum over L chunks; atomicAdd into xsum[b*D+d] ----
// grid (L/16, D/1024, B), block 256; thread owns ONE float4 (d0..d0+3),
// accumulates 16 rows. 1024 blocks -> 4 blocks/CU -> 16 waves/CU: latency
// hiding from occupancy (compiler sinks preloads, R3 post-mortem).
__global__ __launch_bounds__(256) void k_mean_partial(
        const float* __restrict__ x, float* __restrict__ xsum) {
    const int CH = 16;
    int b  = blockIdx.z;
    int l0 = blockIdx.x * CH;
    int d0 = (blockIdx.y * 256 + threadIdx.x) << 2;
    const float* p = x + ((size_t)(b * LL + l0)) * DD + d0;

    float4 acc = {0.f, 0.f, 0.f, 0.f};
#pragma unroll
    for (int l = 0; l < CH; l++) {
        float4 v = *(const float4*)(p + (size_t)l * DD);
        acc.x += v.x; acc.y += v.y; acc.z += v.z; acc.w += v.w;
    }
    float* dst = xsum + b * DD + d0;
    atomicAdd(dst + 0, acc.x);
    atomicAdd(dst + 1, acc.y);
    atomicAdd(dst + 2, acc.z);
    atomicAdd(dst + 3, acc.w);
}

// ---- K2a: gm[b,i] = (1/L) * sum_j h_proj[i,j] * xsum[b,j] ----
// ONE BLOCK PER ROW i (grid 2048); 4 waves each take a 512-col slice;
// LDS combine. 8 blocks/CU.
__global__ __launch_bounds__(256) void k_gm(
        const float* __restrict__ hproj,
        const float* __restrict__ xsum, float* __restrict__ gm) {
    int i = blockIdx.x;
    int wave = threadIdx.x >> 6, lane = threadIdx.x & 63;
    int j0 = wave * 512 + lane * 8;
    const float* row = hproj + (size_t)i * DD;

    float4 h0 = *(const float4*)(row + j0);
    float4 h1 = *(const float4*)(row + j0 + 4);
    float acc[BB];
#pragma unroll
    for (int b = 0; b < BB; b++) {
        float4 xa = *(const float4*)(xsum + b * DD + j0);
        float4 xb = *(const float4*)(xsum + b * DD + j0 + 4);
        acc[b] = h0.x*xa.x + h0.y*xa.y + h0.z*xa.z + h0.w*xa.w
               + h1.x*xb.x + h1.y*xb.y + h1.z*xb.z + h1.w*xb.w;
    }
#pragma unroll
    for (int b = 0; b < BB; b++) {
#pragma unroll
        for (int off = 32; off > 0; off >>= 1) acc[b] += __shfl_down(acc[b], off);
    }
    __shared__ float s[4][BB];
    if (lane == 0) {
#pragma unroll
        for (int b = 0; b < BB; b++) s[wave][b] = acc[b];
    }
    __syncthreads();
    if (threadIdx.x < BB) {
        int b = threadIdx.x;
        float t = s[0][b] + s[1][b] + s[2][b] + s[3][b];
        gm[b * DD + i] = t * (1.0f / LL);
    }
}

// ---- K2b-row: delta[b,i] = DT*( sum_j jup[i,j]*gm[b,j] - gm[b,i]*softplus(r_i) )
// Plain store (first writer of delta). Same structure as k_gm.
__global__ __launch_bounds__(256) void k_delta_row(
        const float* __restrict__ jup,
        const float* __restrict__ rdiag,
        const float* __restrict__ gm, float* __restrict__ delta) {
    int i = blockIdx.x;
    int wave = threadIdx.x >> 6, lane = threadIdx.x & 63;
    int j0 = wave * 512 + lane * 8;
    const float* row = jup + (size_t)i * DD;

    float4 h0 = *(const float4*)(row + j0);
    float4 h1 = *(const float4*)(row + j0 + 4);
    float acc[BB];
#pragma unroll
    for (int b = 0; b < BB; b++) {
        float4 ga = *(const float4*)(gm + b * DD + j0);
        float4 gb = *(const float4*)(gm + b * DD + j0 + 4);
        acc[b] = h0.x*ga.x + h0.y*ga.y + h0.z*ga.z + h0.w*ga.w
               + h1.x*gb.x + h1.y*gb.y + h1.z*gb.z + h1.w*gb.w;
    }
#pragma unroll
    for (int b = 0; b < BB; b++) {
#pragma unroll
        for (int off = 32; off > 0; off >>= 1) acc[b] += __shfl_down(acc[b], off);
    }
    __shared__ float s[4][BB];
    if (lane == 0) {
#pragma unroll
        for (int b = 0; b < BB; b++) s[wave][b] = acc[b];
    }
    __syncthreads();
    if (threadIdx.x < BB) {
        int b = threadIdx.x;
        float r = log1pf(expf(rdiag[i]));  // softplus
        float t = s[0][b] + s[1][b] + s[2][b] + s[3][b];
        delta[b * DD + i] = DTC * (t - gm[b * DD + i] * r);
    }
}

// ---- K2b-col: delta[b,i] -= DT * sum_j gm[b,j]*jup[j,i]  (column access) ----
// grid (D/256, D/16) = (8,128) = 1024 blocks; thread owns column i, block owns
// a 16-wide j chunk. Coalesced across i.
__global__ __launch_bounds__(256) void k_delta_col(
        const float* __restrict__ jup,
        const float* __restrict__ gm, float* __restrict__ delta) {
    const int JT = 16;
    int i  = blockIdx.x * 256 + threadIdx.x;
    int j0 = blockIdx.y * JT;

    float acc[BB] = {0.f, 0.f, 0.f, 0.f};
#pragma unroll
    for (int jj = 0; jj < JT; jj++) {
        float v = jup[(size_t)(j0 + jj) * DD + i];
#pragma unroll
        for (int b = 0; b < BB; b++)
            acc[b] += gm[b * DD + j0 + jj] * v;
    }
#pragma unroll
    for (int b = 0; b < BB; b++) atomicAdd(delta + b * DD + i, -DTC * acc[b]);
}

// ---- K3: main pass. One block per (b,l) row. x' = x + delta[b]; l2-normalize;
// Chebyshev(deg 8); out = x' + 0.1*cheb. float4 I/O. ----
__global__ __launch_bounds__(256) void k_main(
        const float* __restrict__ x,
        const float* __restrict__ delta,
        const float* __restrict__ coeffs,
        float* __restrict__ out) {
    int row = blockIdx.x;           // 0 .. B*L-1
    int b   = row >> 11;            // L = 2048
    int d0  = threadIdx.x << 3;
    size_t base = (size_t)row * DD + d0;

    float4 va = *(const float4*)(x + base);
    float4 vb = *(const float4*)(x + base + 4);
    const float* dl = delta + b * DD + d0;
    float4 da = *(const float4*)dl;
    float4 db = *(const float4*)(dl + 4);
    float xv[8] = {va.x + da.x, va.y + da.y, va.z + da.z, va.w + da.w,
                   vb.x + db.x, vb.y + db.y, vb.z + db.z, vb.w + db.w};

    float ss = 0.f;
#pragma unroll
    for (int k = 0; k < 8; k++) ss += xv[k] * xv[k];
#pragma unroll
    for (int off = 32; off > 0; off >>= 1) ss += __shfl_down(ss, off);
    __shared__ float sred[4];
    int wid = threadIdx.x >> 6, lane = threadIdx.x & 63;
    if (lane == 0) sred[wid] = ss;
    __syncthreads();
    float total = sred[0] + sred[1] + sred[2] + sred[3];
    float rinv = rsqrtf(fmaxf(total, 1e-8f));

    float c[9];
#pragma unroll
    for (int k = 0; k < 9; k++) c[k] = coeffs[k];

    float o[8];
#pragma unroll
    for (int k = 0; k < 8; k++) {
        float xn = xv[k] * rinv;
        float tp = 1.0f, tc = xn;
        float r = c[0] + c[1] * xn;
#pragma unroll
        for (int n = 2; n <= 8; n++) {
            float tn = 2.0f * xn * tc - tp;
            r += c[n] * tn;
            tp = tc; tc = tn;
        }
        o[k] = xv[k] + 0.1f * r;
    }
    float4 oa = {o[0], o[1], o[2], o[3]};
    float4 ob = {o[4], o[5], o[6], o[7]};
    *(float4*)(out + base)     = oa;
    *(float4*)(out + base + 4) = ob;
}

extern "C" void kernel_launch(void* const* d_in, const int* in_sizes, int n_in,
                              void* d_out, int out_size, void* d_ws, size_t ws_size,
                              hipStream_t stream) {
    (void)in_sizes; (void)n_in; (void)out_size; (void)ws_size;
    const float* x      = (const float*)d_in[0];
    const float* jup    = (const float*)d_in[1];
    const float* rdiag  = (const float*)d_in[2];
    const float* hproj  = (const float*)d_in[3];
    const float* coeffs = (const float*)d_in[4];
    float* out = (float*)d_out;

    float* ws    = (float*)d_ws;
    float* xsum  = ws;                 // B*D fp32 (atomic accum; needs zero)
    float* gm    = ws + BB * DD;       // B*D fp32 (plain store)
    float* delta = ws + 2 * BB * DD;   // B*D fp32 (stored by k_delta_row)

    // zero only the atomic-accumulated xsum (ws is poisoned 0xAA each call)
    hipMemsetAsync(d_ws, 0, (size_t)(BB * DD) * sizeof(float), stream);

    k_mean_partial<<<dim3(LL / 16, DD / 1024, BB), 256, 0, stream>>>(x, xsum);
    k_gm<<<DD, 256, 0, stream>>>(hproj, xsum, gm);
    k_delta_row<<<DD, 256, 0, stream>>>(jup, rdiag, gm, delta);
    k_delta_col<<<dim3(DD / 256, DD / 16), 256, 0, stream>>>(jup, gm, delta);
    k_main<<<BB * LL, 256, 0, stream>>>(x, delta, coeffs, out);
}

// Round 5
// 178.615 us; speedup vs baseline: 1.2874x; 1.0962x over previous
//
#include <hip/hip_runtime.h>

// Shapes fixed by setup_inputs(): B=4, L=2048, D=2048. All I/O fp32.
#define BB 4
#define LL 2048
#define DD 2048
#define DTC 0.01f
#define NCHUNK 256   // L / CH
#define CH 8

// ---- K1a: stage-1 column partial sums, NO atomics, plain stores. ----
// grid (NCHUNK, 2, B) = 2048 blocks -> 8 blocks/CU -> 32 waves/CU.
// thread owns one float4 of d; sums CH=8 rows; stores partial[c][b][d].
__global__ __launch_bounds__(256) void k_mean_stage1(
        const float* __restrict__ x, float* __restrict__ partial) {
    int c  = blockIdx.x;
    int b  = blockIdx.z;
    int l0 = c * CH;
    int d0 = blockIdx.y * 1024 + (threadIdx.x << 2);
    const float* p = x + ((size_t)(b * LL + l0)) * DD + d0;

    float4 acc = {0.f, 0.f, 0.f, 0.f};
#pragma unroll
    for (int l = 0; l < CH; l++) {
        float4 v = *(const float4*)(p + (size_t)l * DD);
        acc.x += v.x; acc.y += v.y; acc.z += v.z; acc.w += v.w;
    }
    *(float4*)(partial + ((size_t)(c * BB + b)) * DD + d0) = acc;
}

// ---- K1b: stage-2 reduce partial[c][b][d] over c; atomicAdd into xsum. ----
// grid (2, B, 8): blockIdx.z picks a 32-chunk group. 64 blocks, 64K atomics
// (8 per address), inputs L2/L3-warm.
__global__ __launch_bounds__(256) void k_mean_stage2(
        const float* __restrict__ partial, float* __restrict__ xsum) {
    int d0   = blockIdx.x * 1024 + (threadIdx.x << 2);
    int b    = blockIdx.y;
    int c0   = blockIdx.z * 32;
    float4 acc = {0.f, 0.f, 0.f, 0.f};
#pragma unroll
    for (int cc = 0; cc < 32; cc++) {
        float4 v = *(const float4*)(partial + ((size_t)((c0 + cc) * BB + b)) * DD + d0);
        acc.x += v.x; acc.y += v.y; acc.z += v.z; acc.w += v.w;
    }
    float* dst = xsum + b * DD + d0;
    atomicAdd(dst + 0, acc.x);
    atomicAdd(dst + 1, acc.y);
    atomicAdd(dst + 2, acc.z);
    atomicAdd(dst + 3, acc.w);
}

// ---- K2a: gm[b,i] = (1/L) * sum_j h_proj[i,j] * xsum[b,j] ----
// one block per row i (grid 2048); 4 waves each take a 512-col slice; LDS combine.
__global__ __launch_bounds__(256) void k_gm(
        const float* __restrict__ hproj,
        const float* __restrict__ xsum, float* __restrict__ gm) {
    int i = blockIdx.x;
    int wave = threadIdx.x >> 6, lane = threadIdx.x & 63;
    int j0 = wave * 512 + lane * 8;
    const float* row = hproj + (size_t)i * DD;

    float4 h0 = *(const float4*)(row + j0);
    float4 h1 = *(const float4*)(row + j0 + 4);
    float acc[BB];
#pragma unroll
    for (int b = 0; b < BB; b++) {
        float4 xa = *(const float4*)(xsum + b * DD + j0);
        float4 xb = *(const float4*)(xsum + b * DD + j0 + 4);
        acc[b] = h0.x*xa.x + h0.y*xa.y + h0.z*xa.z + h0.w*xa.w
               + h1.x*xb.x + h1.y*xb.y + h1.z*xb.z + h1.w*xb.w;
    }
#pragma unroll
    for (int b = 0; b < BB; b++) {
#pragma unroll
        for (int off = 32; off > 0; off >>= 1) acc[b] += __shfl_down(acc[b], off);
    }
    __shared__ float s[4][BB];
    if (lane == 0) {
#pragma unroll
        for (int b = 0; b < BB; b++) s[wave][b] = acc[b];
    }
    __syncthreads();
    if (threadIdx.x < BB) {
        int b = threadIdx.x;
        float t = s[0][b] + s[1][b] + s[2][b] + s[3][b];
        gm[b * DD + i] = t * (1.0f / LL);
    }
}

// ---- K2b fused: delta[b,i] = DT*( sum_j jup[i,j]*gm[b,j]          (row part)
//                                 - sum_j jup[j,i]*gm[b,j]          (col part)
//                                 - gm[b,i]*softplus(r_i) )
// delta pre-zeroed; both parts atomicAdd so block order is irrelevant.
// grid = 2048 (row blocks) + 1024 (col blocks).
__global__ __launch_bounds__(256) void k_delta(
        const float* __restrict__ jup,
        const float* __restrict__ rdiag,
        const float* __restrict__ gm, float* __restrict__ delta) {
    if (blockIdx.x < DD) {
        // ---- row part: one block per row i ----
        int i = blockIdx.x;
        int wave = threadIdx.x >> 6, lane = threadIdx.x & 63;
        int j0 = wave * 512 + lane * 8;
        const float* row = jup + (size_t)i * DD;

        float4 h0 = *(const float4*)(row + j0);
        float4 h1 = *(const float4*)(row + j0 + 4);
        float acc[BB];
#pragma unroll
        for (int b = 0; b < BB; b++) {
            float4 ga = *(const float4*)(gm + b * DD + j0);
            float4 gb = *(const float4*)(gm + b * DD + j0 + 4);
            acc[b] = h0.x*ga.x + h0.y*ga.y + h0.z*ga.z + h0.w*ga.w
                   + h1.x*gb.x + h1.y*gb.y + h1.z*gb.z + h1.w*gb.w;
        }
#pragma unroll
        for (int b = 0; b < BB; b++) {
#pragma unroll
            for (int off = 32; off > 0; off >>= 1) acc[b] += __shfl_down(acc[b], off);
        }
        __shared__ float s[4][BB];
        if (lane == 0) {
#pragma unroll
            for (int b = 0; b < BB; b++) s[wave][b] = acc[b];
        }
        __syncthreads();
        if (threadIdx.x < BB) {
            int b = threadIdx.x;
            float r = log1pf(expf(rdiag[i]));  // softplus
            float t = s[0][b] + s[1][b] + s[2][b] + s[3][b];
            atomicAdd(delta + b * DD + i, DTC * (t - gm[b * DD + i] * r));
        }
    } else {
        // ---- col part: cidx selects (i-block, 16-wide j chunk) ----
        const int JT = 16;
        int cidx = blockIdx.x - DD;             // [0, 1024)
        int i  = (cidx & 7) * 256 + threadIdx.x;
        int j0 = (cidx >> 3) * JT;

        float acc[BB] = {0.f, 0.f, 0.f, 0.f};
#pragma unroll
        for (int jj = 0; jj < JT; jj++) {
            float v = jup[(size_t)(j0 + jj) * DD + i];
#pragma unroll
            for (int b = 0; b < BB; b++)
                acc[b] += gm[b * DD + j0 + jj] * v;
        }
#pragma unroll
        for (int b = 0; b < BB; b++) atomicAdd(delta + b * DD + i, -DTC * acc[b]);
    }
}

// ---- K3: main pass. One block per (b,l) row. x' = x + delta[b]; l2-normalize;
// Chebyshev(deg 8); out = x' + 0.1*cheb. float4 I/O. ----
__global__ __launch_bounds__(256) void k_main(
        const float* __restrict__ x,
        const float* __restrict__ delta,
        const float* __restrict__ coeffs,
        float* __restrict__ out) {
    int row = blockIdx.x;           // 0 .. B*L-1
    int b   = row >> 11;            // L = 2048
    int d0  = threadIdx.x << 3;
    size_t base = (size_t)row * DD + d0;

    float4 va = *(const float4*)(x + base);
    float4 vb = *(const float4*)(x + base + 4);
    const float* dl = delta + b * DD + d0;
    float4 da = *(const float4*)dl;
    float4 db = *(const float4*)(dl + 4);
    float xv[8] = {va.x + da.x, va.y + da.y, va.z + da.z, va.w + da.w,
                   vb.x + db.x, vb.y + db.y, vb.z + db.z, vb.w + db.w};

    float ss = 0.f;
#pragma unroll
    for (int k = 0; k < 8; k++) ss += xv[k] * xv[k];
#pragma unroll
    for (int off = 32; off > 0; off >>= 1) ss += __shfl_down(ss, off);
    __shared__ float sred[4];
    int wid = threadIdx.x >> 6, lane = threadIdx.x & 63;
    if (lane == 0) sred[wid] = ss;
    __syncthreads();
    float total = sred[0] + sred[1] + sred[2] + sred[3];
    float rinv = rsqrtf(fmaxf(total, 1e-8f));

    float c[9];
#pragma unroll
    for (int k = 0; k < 9; k++) c[k] = coeffs[k];

    float o[8];
#pragma unroll
    for (int k = 0; k < 8; k++) {
        float xn = xv[k] * rinv;
        float tp = 1.0f, tc = xn;
        float r = c[0] + c[1] * xn;
#pragma unroll
        for (int n = 2; n <= 8; n++) {
            float tn = 2.0f * xn * tc - tp;
            r += c[n] * tn;
            tp = tc; tc = tn;
        }
        o[k] = xv[k] + 0.1f * r;
    }
    float4 oa = {o[0], o[1], o[2], o[3]};
    float4 ob = {o[4], o[5], o[6], o[7]};
    *(float4*)(out + base)     = oa;
    *(float4*)(out + base + 4) = ob;
}

extern "C" void kernel_launch(void* const* d_in, const int* in_sizes, int n_in,
                              void* d_out, int out_size, void* d_ws, size_t ws_size,
                              hipStream_t stream) {
    (void)in_sizes; (void)n_in; (void)out_size; (void)ws_size;
    const float* x      = (const float*)d_in[0];
    const float* jup    = (const float*)d_in[1];
    const float* rdiag  = (const float*)d_in[2];
    const float* hproj  = (const float*)d_in[3];
    const float* coeffs = (const float*)d_in[4];
    float* out = (float*)d_out;

    float* ws      = (float*)d_ws;
    float* xsum    = ws;                      // B*D (atomic accum; zeroed)
    float* delta   = ws + BB * DD;            // B*D (atomic accum; zeroed)
    float* gm      = ws + 2 * BB * DD;        // B*D (plain store)
    float* partial = ws + 3 * BB * DD;        // NCHUNK*B*D = 8 MB (plain store)

    // zero the two atomic-accumulated regions (xsum + delta = 64 KB)
    hipMemsetAsync(d_ws, 0, (size_t)(2 * BB * DD) * sizeof(float), stream);

    k_mean_stage1<<<dim3(NCHUNK, 2, BB), 256, 0, stream>>>(x, partial);
    k_mean_stage2<<<dim3(2, BB, 8), 256, 0, stream>>>(partial, xsum);
    k_gm<<<DD, 256, 0, stream>>>(hproj, xsum, gm);
    k_delta<<<DD + DD / 2, 256, 0, stream>>>(jup, rdiag, gm, delta);
    k_main<<<BB * LL, 256, 0, stream>>>(x, delta, coeffs, out);
}